// Round 4
// baseline (1012.309 us; speedup 1.0000x reference)
//
#include <hip/hip_runtime.h>
#include <cmath>

#define N_B 32
#define C_B 64
#define D_B 128
#define DD  (D_B*D_B)          // 16384
// LDS tile: row-major [128][128] f32, physical float4 slot = c4 ^ (row&7).
// Bank-quad = slot mod 8; all access patterns verified uniform across quads.
#define BUF (D_B*D_B)          // 16384 floats per tile buffer
#define SMEM_FLOATS (2*BUF + D_B*16 + D_B + D_B + 16)
#define SMEM_BYTES  (SMEM_FLOATS*4)

#define COMP(v,t) ((t)==0?(v).x:(t)==1?(v).y:(t)==2?(v).z:(v).w)

// swizzled float4 accessor: logical (row, c4) -> physical
__device__ __forceinline__ float4* L4(float* buf, int row, int c4) {
    return (float4*)(buf + (row << 7)) + (c4 ^ (row & 7));
}

// ---------------- K0: rdi[n,c,i] = 1/sqrt(max(|in[n,c,i,i]|,1e-4)) ----------------
__global__ void k_rdi(const float* __restrict__ in, float* __restrict__ rdi) {
    int t = blockIdx.x * 256 + threadIdx.x;       // [0, N*C*D)
    int i = t & (D_B - 1);
    int mat = t >> 7;                              // n*C + c
    float v = fabsf(in[(size_t)mat * DD + (size_t)i * D_B + i]);
    rdi[t] = 1.0f / sqrtf(fmaxf(v, 1e-4f));
}

// ---------------- K1: one-output channel mix (launched twice: Q then K) ------------
// 64 accumulators -> ~90 VGPR -> 4+ waves/SIMD (vs 2 for the fused 128-acc version).
__global__ __launch_bounds__(256, 4) void k_mix1(
        const float* __restrict__ in, const float* __restrict__ rdi,
        const float* __restrict__ w, float* __restrict__ xo) {
    __shared__ float ws[C_B*C_B];
    const int tid = threadIdx.x;
    #pragma unroll
    for (int q = 0; q < 16; ++q) ws[q*256 + tid] = w[q*256 + tid];
    __syncthreads();
    const int n = blockIdx.y;
    const int p = blockIdx.x * 256 + tid;          // pixel within D*D
    const int i = p >> 7, j = p & (D_B - 1);
    const float* inb  = in  + (size_t)n * C_B * DD + p;
    const float* rdib = rdi + (size_t)n * C_B * D_B;
    float acc[C_B];
    #pragma unroll
    for (int k = 0; k < C_B; ++k) acc[k] = 0.f;
    float xr0 = inb[0];
    float xr1 = inb[DD];                           // 2-deep prefetch pipeline
    for (int c = 0; c < C_B; ++c) {
        float x = xr0 * rdib[c*D_B + i] * rdib[c*D_B + j];
        x = fminf(fmaxf(x, -1.f), 1.f);
        xr0 = xr1;
        if (c + 2 < C_B) xr1 = inb[(size_t)(c+2) * DD];
        const float4* w4 = (const float4*)(ws + c*C_B);
        #pragma unroll
        for (int k4 = 0; k4 < 16; ++k4) {
            float4 a = w4[k4];
            acc[4*k4+0] += x*a.x; acc[4*k4+1] += x*a.y;
            acc[4*k4+2] += x*a.z; acc[4*k4+3] += x*a.w;
        }
    }
    float* o = xo + (size_t)n * C_B * DD + p;
    #pragma unroll
    for (int k = 0; k < C_B; ++k) o[(size_t)k*DD] = acc[k];
}

// ---------------- K2: per-(n,k) core: bilinear form, soft_pd_max, AXA, residual ----
// Per-thread tile: rows r0..r0+3, cols {4cg..4cg+3} U {64+4cg..64+4cg+3}.
// Column split (not cg*8) => B-operand ds_read_b128 covers 16 consecutive c4
// slots -> 2-way bank aliasing (free) instead of 4-way.
__global__ __launch_bounds__(512, 2) void k_core(
        const float* __restrict__ in, const float* __restrict__ rdi,
        const float* xwq,                       // aliases `out` — intentionally not restrict
        const float* __restrict__ xwk,
        const float* __restrict__ lam, float* out) {
    extern __shared__ float sm[];
    float* bufA = sm;                  // XWQ -> T1 -> A^T
    float* bufB = sm + BUF;            // XWK -> X  -> T2
    float* rs   = sm + 2*BUF;          // [128][16] row partial sums
    float* dia  = rs + D_B*16;         // [128]
    float* rdl  = dia + D_B;           // [128]
    float* wred = rdl + D_B;           // [16]

    const int tid = threadIdx.x;
    const int bid = blockIdx.x;                 // n*64 + k
    const size_t base = (size_t)bid * DD;
    const int rg = tid >> 4, cg = tid & 15;
    const int r0 = rg * 4;
    const int j0a = cg * 4, j0b = 64 + cg * 4;  // split column groups
    const int srow = tid >> 2, scol = (tid & 3) * 32;   // staging map: 32 floats/thread
    const int sc4 = (tid & 3) * 8;

    // ---- stage XWQ -> bufA, XWK -> bufB
    {
        const float* gq = xwq + base + (size_t)srow*D_B + scol;
        const float* gk = xwk + base + (size_t)srow*D_B + scol;
        #pragma unroll
        for (int t = 0; t < 8; ++t) {
            *L4(bufA, srow, sc4 + t) = *(const float4*)(gq + 4*t);
            *L4(bufB, srow, sc4 + t) = *(const float4*)(gk + 4*t);
        }
    }
    __syncthreads();

    // ---- T1 = XWK^T @ XWQ : T1[r][j] = sum_kk XWK[kk][r] * XWQ[kk][j]
    float acc[4][8];
    #pragma unroll
    for (int i = 0; i < 4; ++i)
        #pragma unroll
        for (int j = 0; j < 8; ++j) acc[i][j] = 0.f;
    #pragma unroll 4
    for (int kk = 0; kk < D_B; ++kk) {
        float4 a  = *L4(bufB, kk, rg);        // XWK[kk][r0..r0+3]
        float4 b0 = *L4(bufA, kk, cg);        // XWQ[kk][j0a..]
        float4 b1 = *L4(bufA, kk, 16 + cg);   // XWQ[kk][j0b..]
        float av[4] = {a.x, a.y, a.z, a.w};
        float bv[8] = {b0.x,b0.y,b0.z,b0.w,b1.x,b1.y,b1.z,b1.w};
        #pragma unroll
        for (int i = 0; i < 4; ++i)
            #pragma unroll
            for (int j = 0; j < 8; ++j) acc[i][j] += av[i]*bv[j];
    }
    __syncthreads();
    // write T1 -> bufA (XWQ consumed); logical row-major layout preserved
    #pragma unroll
    for (int i = 0; i < 4; ++i) {
        float4 v0 = {acc[i][0],acc[i][1],acc[i][2],acc[i][3]};
        float4 v1 = {acc[i][4],acc[i][5],acc[i][6],acc[i][7]};
        *L4(bufA, r0+i, cg)      = v0;
        *L4(bufA, r0+i, 16 + cg) = v1;
    }
    // prefetch inputs tile + rdi for later X staging (hidden under next matmul)
    float4 xin[8], rcv[8];
    const float* rdib = rdi + (size_t)bid * D_B;
    const float xrr = rdib[srow];
    #pragma unroll
    for (int t = 0; t < 8; ++t) {
        xin[t] = *(const float4*)(in + base + (size_t)srow*D_B + scol + 4*t);
        rcv[t] = *(const float4*)(rdib + scol + 4*t);
    }
    __syncthreads();

    // ---- A_pre = T1 @ XWK : acc2[r][j] = sum_kk T1[r][kk]*XWK[kk][j]
    float acc2[4][8];
    #pragma unroll
    for (int i = 0; i < 4; ++i)
        #pragma unroll
        for (int j = 0; j < 8; ++j) acc2[i][j] = 0.f;
    for (int kk4 = 0; kk4 < 32; ++kk4) {
        float4 av4[4];
        #pragma unroll
        for (int i = 0; i < 4; ++i)
            av4[i] = *L4(bufA, r0+i, kk4);
        #pragma unroll
        for (int t = 0; t < 4; ++t) {
            float4 b0 = *L4(bufB, 4*kk4+t, cg);
            float4 b1 = *L4(bufB, 4*kk4+t, 16 + cg);
            float bv[8] = {b0.x,b0.y,b0.z,b0.w,b1.x,b1.y,b1.z,b1.w};
            #pragma unroll
            for (int i = 0; i < 4; ++i) {
                float a = COMP(av4[i], t);
                #pragma unroll
                for (int j = 0; j < 8; ++j) acc2[i][j] += a*bv[j];
            }
        }
    }

    // ---- soft_pd_max on acc2 (whole 128x128 matrix per block)
    float m = -3.0e38f;
    #pragma unroll
    for (int i = 0; i < 4; ++i)
        #pragma unroll
        for (int j = 0; j < 8; ++j) m = fmaxf(m, acc2[i][j]);
    #pragma unroll
    for (int off = 32; off >= 1; off >>= 1) m = fmaxf(m, __shfl_xor(m, off));
    if ((tid & 63) == 0) wred[tid >> 6] = m;
    __syncthreads();
    float M = wred[0];
    #pragma unroll
    for (int w = 1; w < 8; ++w) M = fmaxf(M, wred[w]);

    float ps[4] = {0.f, 0.f, 0.f, 0.f};
    #pragma unroll
    for (int i = 0; i < 4; ++i)
        #pragma unroll
        for (int j = 0; j < 8; ++j) {
            float e = expf(acc2[i][j] - M);
            acc2[i][j] = e;
            ps[i] += e;
        }
    #pragma unroll
    for (int i = 0; i < 4; ++i) rs[(r0+i)*16 + cg] = ps[i];
    __syncthreads();
    if (tid < D_B) {
        float s = 0.f;
        #pragma unroll
        for (int c2 = 0; c2 < 16; ++c2) s += rs[tid*16 + c2];
        dia[tid] = s;
    }
    __syncthreads();
    if (tid < 64) {
        float s = dia[tid] + dia[tid + 64];
        #pragma unroll
        for (int off = 32; off >= 1; off >>= 1) s += __shfl_xor(s, off);
        if (tid == 0) wred[8] = s;
    }
    __syncthreads();
    const float total = wred[8];
    if (tid < D_B) {
        float d = dia[tid];
        d = fmaxf(d, total * 1e-5f);   // sum(dia)/100000
        d = fmaxf(d, 1e-5f);
        rdl[tid] = 1.0f / sqrtf(d);
    }
    __syncthreads();

    // A = e * rdl[r] * rdl[c]; store A^T into bufA; store X into bufB
    float rrv[4], rcw[8];
    #pragma unroll
    for (int i = 0; i < 4; ++i) rrv[i] = rdl[r0+i];
    #pragma unroll
    for (int j = 0; j < 4; ++j) { rcw[j] = rdl[j0a+j]; rcw[4+j] = rdl[j0b+j]; }
    #pragma unroll
    for (int i = 0; i < 4; ++i)
        #pragma unroll
        for (int j = 0; j < 8; ++j) acc2[i][j] *= rrv[i]*rcw[j];
    #pragma unroll
    for (int jj = 0; jj < 4; ++jj) {
        float4 v0 = {acc2[0][jj],   acc2[1][jj],   acc2[2][jj],   acc2[3][jj]};
        float4 v1 = {acc2[0][4+jj], acc2[1][4+jj], acc2[2][4+jj], acc2[3][4+jj]};
        *L4(bufA, j0a+jj, rg) = v0;   // A^T[col][r0..r0+3]
        *L4(bufA, j0b+jj, rg) = v1;
    }
    #pragma unroll
    for (int t = 0; t < 8; ++t) {
        float4 x = xin[t], rq = rcv[t];
        x.x = fminf(fmaxf(x.x*xrr*rq.x, -1.f), 1.f);
        x.y = fminf(fmaxf(x.y*xrr*rq.y, -1.f), 1.f);
        x.z = fminf(fmaxf(x.z*xrr*rq.z, -1.f), 1.f);
        x.w = fminf(fmaxf(x.w*xrr*rq.w, -1.f), 1.f);
        *L4(bufB, srow, sc4 + t) = x;
    }
    __syncthreads();

    // ---- T2 = A @ X : T2[r][j] = sum_kk AT[kk][r] * X[kk][j]
    float acc3[4][8];
    #pragma unroll
    for (int i = 0; i < 4; ++i)
        #pragma unroll
        for (int j = 0; j < 8; ++j) acc3[i][j] = 0.f;
    #pragma unroll 4
    for (int kk = 0; kk < D_B; ++kk) {
        float4 a  = *L4(bufA, kk, rg);        // A[r0..r0+3][kk]
        float4 b0 = *L4(bufB, kk, cg);        // X[kk][j0a..]
        float4 b1 = *L4(bufB, kk, 16 + cg);
        float av[4] = {a.x, a.y, a.z, a.w};
        float bv[8] = {b0.x,b0.y,b0.z,b0.w,b1.x,b1.y,b1.z,b1.w};
        #pragma unroll
        for (int i = 0; i < 4; ++i)
            #pragma unroll
            for (int j = 0; j < 8; ++j) acc3[i][j] += av[i]*bv[j];
    }
    __syncthreads();
    // write T2 -> bufB (X consumed)
    #pragma unroll
    for (int i = 0; i < 4; ++i) {
        float4 v0 = {acc3[i][0],acc3[i][1],acc3[i][2],acc3[i][3]};
        float4 v1 = {acc3[i][4],acc3[i][5],acc3[i][6],acc3[i][7]};
        *L4(bufB, r0+i, cg)      = v0;
        *L4(bufB, r0+i, 16 + cg) = v1;
    }
    __syncthreads();

    // ---- AXA = T2 @ A^T : acc4[r][j] = sum_kk T2[r][kk] * AT[kk][j]
    float acc4[4][8];
    #pragma unroll
    for (int i = 0; i < 4; ++i)
        #pragma unroll
        for (int j = 0; j < 8; ++j) acc4[i][j] = 0.f;
    for (int kk4 = 0; kk4 < 32; ++kk4) {
        float4 av4[4];
        #pragma unroll
        for (int i = 0; i < 4; ++i)
            av4[i] = *L4(bufB, r0+i, kk4);
        #pragma unroll
        for (int t = 0; t < 4; ++t) {
            float4 b0 = *L4(bufA, 4*kk4+t, cg);
            float4 b1 = *L4(bufA, 4*kk4+t, 16 + cg);
            float bv[8] = {b0.x,b0.y,b0.z,b0.w,b1.x,b1.y,b1.z,b1.w};
            #pragma unroll
            for (int i = 0; i < 4; ++i) {
                float a = COMP(av4[i], t);
                #pragma unroll
                for (int j = 0; j < 8; ++j) acc4[i][j] += a*bv[j];
            }
        }
    }

    // ---- epilogue: out = inputs + lam * AXA (two split column groups)
    const float l = lam[bid & 63];
    #pragma unroll
    for (int i = 0; i < 4; ++i) {
        float4 vin0 = *(const float4*)(in + base + (size_t)(r0+i)*D_B + j0a);
        float4 vin1 = *(const float4*)(in + base + (size_t)(r0+i)*D_B + j0b);
        float4 o0, o1;
        o0.x = vin0.x + l*acc4[i][0]; o0.y = vin0.y + l*acc4[i][1];
        o0.z = vin0.z + l*acc4[i][2]; o0.w = vin0.w + l*acc4[i][3];
        o1.x = vin1.x + l*acc4[i][4]; o1.y = vin1.y + l*acc4[i][5];
        o1.z = vin1.z + l*acc4[i][6]; o1.w = vin1.w + l*acc4[i][7];
        *(float4*)(out + base + (size_t)(r0+i)*D_B + j0a) = o0;
        *(float4*)(out + base + (size_t)(r0+i)*D_B + j0b) = o1;
    }
}

extern "C" void kernel_launch(void* const* d_in, const int* in_sizes, int n_in,
                              void* d_out, int out_size, void* d_ws, size_t ws_size,
                              hipStream_t stream) {
    const float* in  = (const float*)d_in[0];
    const float* wq  = (const float*)d_in[1];
    const float* wk  = (const float*)d_in[2];
    const float* lam = (const float*)d_in[3];
    float* out = (float*)d_out;

    // workspace layout: XWK (N*C*D*D floats) then rdi (N*C*D floats)
    float* xwk = (float*)d_ws;
    float* rdi = xwk + (size_t)N_B*C_B*DD;
    // XWQ lives in d_out: block (n,k) is the only consumer of XWQ[n,k] and
    // reads it into LDS before writing its output slice there.
    float* xwq = out;

    hipFuncSetAttribute((const void*)k_core,
                        hipFuncAttributeMaxDynamicSharedMemorySize, SMEM_BYTES);

    k_rdi<<<(N_B*C_B*D_B)/256, 256, 0, stream>>>(in, rdi);
    k_mix1<<<dim3(DD/256, N_B), 256, 0, stream>>>(in, rdi, wq, xwq);
    k_mix1<<<dim3(DD/256, N_B), 256, 0, stream>>>(in, rdi, wk, xwk);
    k_core<<<N_B*C_B, 512, SMEM_BYTES, stream>>>(in, rdi, xwq, xwk, lam, out);
}

// Round 5
// 681.377 us; speedup vs baseline: 1.4857x; 1.4857x over previous
//
#include <hip/hip_runtime.h>
#include <cmath>

#define N_B 32
#define C_B 64
#define D_B 128
#define DD  (D_B*D_B)          // 16384

typedef __attribute__((ext_vector_type(8))) _Float16 half8;
typedef __attribute__((ext_vector_type(16))) float f32x16;

// LDS: 4 f16 matrices (hi/lo pairs) + f32 reduction scratch
#define SMEM_BYTES (4*DD*2 + (2*D_B + D_B + 16)*4)

// f16 matrix [row][128], 16B-granule XOR swizzle: logical col c lives at
// granule (c>>3)^(row&7), offset c&7.  Bijective per row; every MFMA frag
// (8 consecutive k at 8-aligned base) is one aligned 16B read, conflict-free.
__device__ __forceinline__ int fidx(int row, int col) {
    return (row << 7) + ((((col >> 3) ^ (row & 7)) << 3) | (col & 7));
}
__device__ __forceinline__ const half8* fragp(const _Float16* buf, int row, int g) {
    return (const half8*)(buf + (row << 7) + ((g ^ (row & 7)) << 3));
}

// ---------------- K0: rdi[n,c,i] = 1/sqrt(max(|in[n,c,i,i]|,1e-4)) ----------------
__global__ void k_rdi(const float* __restrict__ in, float* __restrict__ rdi) {
    int t = blockIdx.x * 256 + threadIdx.x;       // [0, N*C*D)
    int i = t & (D_B - 1);
    int mat = t >> 7;                              // n*C + c
    float v = fabsf(in[(size_t)mat * DD + (size_t)i * D_B + i]);
    rdi[t] = 1.0f / sqrtf(fmaxf(v, 1e-4f));
}

// ---------------- K1: XWQ / XWK channel mix (r3 fused version, known-good) --------
__global__ __launch_bounds__(256, 2) void k_mix(
        const float* __restrict__ in, const float* __restrict__ rdi,
        const float* __restrict__ wq, const float* __restrict__ wk,
        float* __restrict__ xwq, float* __restrict__ xwk) {
    __shared__ float wqs[C_B*C_B];
    __shared__ float wks[C_B*C_B];
    const int tid = threadIdx.x;
    #pragma unroll
    for (int q = 0; q < 16; ++q) {
        wqs[q*256 + tid] = wq[q*256 + tid];
        wks[q*256 + tid] = wk[q*256 + tid];
    }
    __syncthreads();
    const int n = blockIdx.y;
    const int p = blockIdx.x * 256 + tid;
    const int i = p >> 7, j = p & (D_B - 1);
    const float* inb  = in  + (size_t)n * C_B * DD + p;
    const float* rdib = rdi + (size_t)n * C_B * D_B;
    float accq[C_B], acck[C_B];
    #pragma unroll
    for (int k = 0; k < C_B; ++k) { accq[k] = 0.f; acck[k] = 0.f; }
    float xraw = inb[0];
    for (int c = 0; c < C_B; ++c) {
        float x = xraw * rdib[c*D_B + i] * rdib[c*D_B + j];
        x = fminf(fmaxf(x, -1.f), 1.f);
        if (c + 1 < C_B) xraw = inb[(size_t)(c+1) * DD];
        const float4* wq4 = (const float4*)(wqs + c*C_B);
        const float4* wk4 = (const float4*)(wks + c*C_B);
        #pragma unroll
        for (int k4 = 0; k4 < 16; ++k4) {
            float4 a = wq4[k4];
            float4 b = wk4[k4];
            accq[4*k4+0] += x*a.x; accq[4*k4+1] += x*a.y;
            accq[4*k4+2] += x*a.z; accq[4*k4+3] += x*a.w;
            acck[4*k4+0] += x*b.x; acck[4*k4+1] += x*b.y;
            acck[4*k4+2] += x*b.z; acck[4*k4+3] += x*b.w;
        }
    }
    float* oq = xwq + (size_t)n * C_B * DD + p;
    float* ok = xwk + (size_t)n * C_B * DD + p;
    #pragma unroll
    for (int k = 0; k < C_B; ++k) {
        oq[(size_t)k*DD] = accq[k];
        ok[(size_t)k*DD] = acck[k];
    }
}

// ---------------- K2: MFMA core (f16 split-2, 3-product ~= fp32 precision) --------
// 8 waves: wave w owns D-rows 32*(w>>1).. and cols 64*(w&1)..  (2 tiles of 32x32).
// mfma_f32_32x32x16_f16:  A[m][k]: m=lane&31, k=(lane>>5)*8+i
//                         B[k][n]: n=lane&31, k=(lane>>5)*8+i
//                         D: col=lane&31, row=(reg&3)+8*(reg>>2)+4*(lane>>5)
__global__ __launch_bounds__(512, 1) void k_core(
        const float* __restrict__ in, const float* __restrict__ rdi,
        const float* xwq,                       // aliases `out` — intentionally not restrict
        const float* __restrict__ xwk,
        const float* __restrict__ lam, float* out) {
    extern __shared__ _Float16 smh[];
    _Float16* M0h = smh;                 // XWK^T -> A -> (A stays)
    _Float16* M0l = smh + DD;
    _Float16* M1h = smh + 2*DD;          // XWQ^T -> T1 -> X^T -> T2
    _Float16* M1l = smh + 3*DD;
    float* rs   = (float*)(smh + 4*DD);  // [128][2] row partial sums
    float* rdl  = rs + 2*D_B;            // [128]
    float* wred = rdl + D_B;             // [16]

    const int tid = threadIdx.x;
    const int bid = blockIdx.x;          // n*64 + k
    const size_t base = (size_t)bid * DD;
    const int lane = tid & 63;
    const int w = tid >> 6;
    const int lrow = lane & 31, lhalf = lane >> 5;
    const int m0 = 32 * (w >> 1);        // row block
    const int n0 = 64 * (w & 1);         // col half
    const int srow = tid & 127;          // staging: row, 32-col chunk
    const int sj0  = (tid >> 7) * 32;
    const float* rdib = rdi + (size_t)bid * D_B;

    // ---- stage XWK^T -> M0, XWQ^T -> M1 (hi/lo, transposed, swizzled)
    {
        const float* gk = xwk + base + (size_t)srow * D_B + sj0;
        const float* gq = xwq + base + (size_t)srow * D_B + sj0;
        #pragma unroll
        for (int t = 0; t < 8; ++t) {
            float4 vk = *(const float4*)(gk + 4*t);
            float4 vq = *(const float4*)(gq + 4*t);
            float ak[4] = {vk.x, vk.y, vk.z, vk.w};
            float aq[4] = {vq.x, vq.y, vq.z, vq.w};
            #pragma unroll
            for (int u = 0; u < 4; ++u) {
                int idx = fidx(sj0 + 4*t + u, srow);   // dst[col][row] = transpose
                _Float16 hk = (_Float16)ak[u];
                M0h[idx] = hk; M0l[idx] = (_Float16)(ak[u] - (float)hk);
                _Float16 hq = (_Float16)aq[u];
                M1h[idx] = hq; M1l[idx] = (_Float16)(aq[u] - (float)hq);
            }
        }
    }
    __syncthreads();

    f32x16 acc[2];

#define ZERO_ACC() { _Pragma("unroll") for (int ct = 0; ct < 2; ++ct) { _Pragma("unroll") for (int r = 0; r < 16; ++r) acc[ct][r] = 0.f; } }

#define GEMM(Ah, Al, Bh, Bl) { \
    _Pragma("unroll") \
    for (int kt = 0; kt < 8; ++kt) { \
        int g = kt*2 + lhalf; \
        half8 aH = *fragp(Ah, m0 + lrow, g); \
        half8 aL = *fragp(Al, m0 + lrow, g); \
        _Pragma("unroll") \
        for (int ct = 0; ct < 2; ++ct) { \
            half8 bH = *fragp(Bh, n0 + 32*ct + lrow, g); \
            half8 bL = *fragp(Bl, n0 + 32*ct + lrow, g); \
            acc[ct] = __builtin_amdgcn_mfma_f32_32x32x16_f16(aH, bH, acc[ct], 0, 0, 0); \
            acc[ct] = __builtin_amdgcn_mfma_f32_32x32x16_f16(aH, bL, acc[ct], 0, 0, 0); \
            acc[ct] = __builtin_amdgcn_mfma_f32_32x32x16_f16(aL, bH, acc[ct], 0, 0, 0); \
        } \
    } }

#define STORE_D(Mh, Ml) { \
    _Pragma("unroll") \
    for (int ct = 0; ct < 2; ++ct) { \
        _Pragma("unroll") \
        for (int r = 0; r < 16; ++r) { \
            int row = m0 + (r&3) + 8*(r>>2) + 4*lhalf; \
            int col = n0 + 32*ct + lrow; \
            float v = acc[ct][r]; \
            _Float16 h = (_Float16)v; \
            int idx = fidx(row, col); \
            (Mh)[idx] = h; (Ml)[idx] = (_Float16)(v - (float)h); \
        } \
    } }

    // ---- GEMM1: T1 = XWK^T @ XWQ   (A-op = M0, B-op = M1)
    ZERO_ACC();
    GEMM(M0h, M0l, M1h, M1l);
    __syncthreads();
    STORE_D(M1h, M1l);                   // T1 -> M1 (over XWQ^T)
    __syncthreads();

    // ---- GEMM2: A_pre = T1 @ XWK   (A-op = M1, B-op = M0: M0[n][k]=XWK[k][n])
    ZERO_ACC();
    GEMM(M1h, M1l, M0h, M0l);

    // ---- soft_pd_max on acc (whole 128x128 per block)
    float mx = -3.0e38f;
    #pragma unroll
    for (int ct = 0; ct < 2; ++ct)
        #pragma unroll
        for (int r = 0; r < 16; ++r) mx = fmaxf(mx, acc[ct][r]);
    #pragma unroll
    for (int off = 32; off >= 1; off >>= 1) mx = fmaxf(mx, __shfl_xor(mx, off));
    if (lane == 0) wred[w] = mx;
    __syncthreads();
    float M = wred[0];
    #pragma unroll
    for (int q = 1; q < 8; ++q) M = fmaxf(M, wred[q]);

    float ps[16];
    #pragma unroll
    for (int r = 0; r < 16; ++r) {
        float e0 = __expf(acc[0][r] - M) * 0.f;  // placeholder never used
        (void)e0;
        float a0 = expf(acc[0][r] - M);
        float a1 = expf(acc[1][r] - M);
        acc[0][r] = a0; acc[1][r] = a1;
        ps[r] = a0 + a1;
    }
    // row sums: reduce across the 32 lrow lanes (same lhalf)
    #pragma unroll
    for (int r = 0; r < 16; ++r) {
        float p = ps[r];
        p += __shfl_xor(p, 1);  p += __shfl_xor(p, 2);
        p += __shfl_xor(p, 4);  p += __shfl_xor(p, 8);
        p += __shfl_xor(p, 16);
        ps[r] = p;
    }
    if (lrow == 0) {
        #pragma unroll
        for (int r = 0; r < 16; ++r) {
            int row = m0 + (r&3) + 8*(r>>2) + 4*lhalf;
            rs[row*2 + (w & 1)] = ps[r];
        }
    }
    __syncthreads();
    if (tid < D_B) {
        float d = rs[tid*2] + rs[tid*2 + 1];
        rdl[tid] = d;
        float s = d;
        #pragma unroll
        for (int off = 32; off >= 1; off >>= 1) s += __shfl_xor(s, off);
        if ((tid & 63) == 0) wred[8 + (tid >> 6)] = s;
    }
    __syncthreads();
    if (tid < D_B) {
        float total = wred[8] + wred[9];
        float d = rdl[tid];
        d = fmaxf(d, total * 1e-5f);     // sum(dia)/100000
        d = fmaxf(d, 1e-5f);
        rdl[tid] = 1.0f / sqrtf(d);
    }
    __syncthreads();

    // ---- A = e * rdl[row] * rdl[col] -> M0 (row-major [m][k]; serves GEMM3-A & GEMM4-B)
    {
        float rr[16];
        #pragma unroll
        for (int r = 0; r < 16; ++r) rr[r] = rdl[m0 + (r&3) + 8*(r>>2) + 4*lhalf];
        float rc0 = rdl[n0 + lrow];
        float rc1 = rdl[n0 + 32 + lrow];
        #pragma unroll
        for (int ct = 0; ct < 2; ++ct) {
            float rc = ct ? rc1 : rc0;
            #pragma unroll
            for (int r = 0; r < 16; ++r) {
                int row = m0 + (r&3) + 8*(r>>2) + 4*lhalf;
                int col = n0 + 32*ct + lrow;
                float v = acc[ct][r] * rr[r] * rc;
                _Float16 h = (_Float16)v;
                int idx = fidx(row, col);
                M0h[idx] = h; M0l[idx] = (_Float16)(v - (float)h);
            }
        }
    }
    // ---- stage X^T -> M1 (over T1): x = clip(in*rdi_r*rdi_c), dst[col][row]
    {
        const float rrX = rdib[srow];
        const float* gi = in + base + (size_t)srow * D_B + sj0;
        #pragma unroll
        for (int t = 0; t < 8; ++t) {
            float4 v  = *(const float4*)(gi + 4*t);
            float4 rc = *(const float4*)(rdib + sj0 + 4*t);
            float vv[4] = {v.x, v.y, v.z, v.w};
            float cc[4] = {rc.x, rc.y, rc.z, rc.w};
            #pragma unroll
            for (int u = 0; u < 4; ++u) {
                float x = fminf(fmaxf(vv[u] * rrX * cc[u], -1.f), 1.f);
                int idx = fidx(sj0 + 4*t + u, srow);
                _Float16 h = (_Float16)x;
                M1h[idx] = h; M1l[idx] = (_Float16)(x - (float)h);
            }
        }
    }
    __syncthreads();

    // ---- GEMM3: T2 = A @ X   (A-op = M0, B-op = M1: M1[n][k]=X[k][n])
    ZERO_ACC();
    GEMM(M0h, M0l, M1h, M1l);
    __syncthreads();
    STORE_D(M1h, M1l);                   // T2 -> M1 (over X^T)
    __syncthreads();

    // ---- GEMM4: AXA = T2 @ A^T  (A-op = M1, B-op = M0: M0[n][k]=A[n][k])
    ZERO_ACC();
    GEMM(M1h, M1l, M0h, M0l);

    // ---- epilogue: out = inputs + lam * AXA
    const float l = lam[bid & 63];
    #pragma unroll
    for (int ct = 0; ct < 2; ++ct) {
        #pragma unroll
        for (int r = 0; r < 16; ++r) {
            int row = m0 + (r&3) + 8*(r>>2) + 4*lhalf;
            int col = n0 + 32*ct + lrow;
            size_t off = base + (size_t)row * D_B + col;
            out[off] = in[off] + l * acc[ct][r];
        }
    }
#undef ZERO_ACC
#undef GEMM
#undef STORE_D
}

extern "C" void kernel_launch(void* const* d_in, const int* in_sizes, int n_in,
                              void* d_out, int out_size, void* d_ws, size_t ws_size,
                              hipStream_t stream) {
    const float* in  = (const float*)d_in[0];
    const float* wq  = (const float*)d_in[1];
    const float* wk  = (const float*)d_in[2];
    const float* lam = (const float*)d_in[3];
    float* out = (float*)d_out;

    // workspace: XWK (N*C*D*D f32) then rdi (N*C*D f32); XWQ lives in d_out
    float* xwk = (float*)d_ws;
    float* rdi = xwk + (size_t)N_B*C_B*DD;
    float* xwq = out;

    hipFuncSetAttribute((const void*)k_core,
                        hipFuncAttributeMaxDynamicSharedMemorySize, SMEM_BYTES);

    k_rdi<<<(N_B*C_B*D_B)/256, 256, 0, stream>>>(in, rdi);
    k_mix<<<dim3(DD/256, N_B), 256, 0, stream>>>(in, rdi, wq, wk, xwq, xwk);
    k_core<<<N_B*C_B, 512, SMEM_BYTES, stream>>>(in, rdi, xwq, xwk, lam, out);
}